// Round 8
// baseline (76.652 us; speedup 1.0000x reference)
//
#include <hip/hip_runtime.h>

#define B_    32
#define CIN_  64
#define COUT_ 64
#define IMG_  128
#define W4_   32                 // float4 per row
#define PIX4_ 4096               // float4 per plane
#define NPOS_ (B_ * PIX4_)       // 131072 float4 positions
#define NG_   4                  // channel groups (partial planes)

// ---- Kernel A: 4-group partial channel sums. Grid (512,4) = 2048 blocks =
// 8 blocks/CU = 32 waves/CU. Each thread: 1 position, 16-channel walk with
// 16 independent float4 loads in flight. Reads 134 MB, writes 16 MB. ----
__global__ __launch_bounds__(256) void ch_sum4(const float* __restrict__ x,
                                               float* __restrict__ part) {
    const int g = blockIdx.y;                      // 0..3 channel group
    const int i = blockIdx.x * 256 + threadIdx.x;  // 0..NPOS_-1
    const int b = i >> 12;
    const int p = i & (PIX4_ - 1);

    const float4* xp = reinterpret_cast<const float4*>(x)
                     + ((size_t)b * CIN_ + (size_t)g * 16) * PIX4_ + p;

    float4 a = make_float4(0.f, 0.f, 0.f, 0.f);
#pragma unroll
    for (int c = 0; c < 16; ++c) {
        float4 v = xp[(size_t)c * PIX4_];
        a.x += v.x; a.y += v.y; a.z += v.z; a.w += v.w;
    }
    reinterpret_cast<float4*>(part)[(size_t)g * NPOS_ + i] = a;
}

// ---- Kernel B: no LDS. Block = (b, co, half-plane). Each thread owns 8
// consecutive rows at fixed w4: loads its 10-row float4 column from the four
// L2-resident partial planes (40 coalesced b128 loads), halo scalars via
// shfl, streams 8 sequential float4 stores. ----
__global__ __launch_bounds__(256) void conv_shfl(const float* __restrict__ part,
                                                 const float* __restrict__ kern,
                                                 const float* __restrict__ bias,
                                                 float* __restrict__ out) {
    const int n   = blockIdx.x;                    // 0..4095
    const int swz = (n & 7) * 512 + (n >> 3);      // bijective XCD chunking
    const int co   = swz & 63;
    const int half = (swz >> 6) & 1;
    const int b    = swz >> 7;
    const int tid  = threadIdx.x;
    const int w4   = tid & 31;
    const int rb   = (tid >> 5) * 8;               // local output rows rb..rb+7
    const int r0   = half * 64;

    const float4* pb = reinterpret_cast<const float4*>(part) + (size_t)b * PIX4_;

    // 10-row column of summed partials (C), all loads issued up front.
    float4 C[10];
#pragma unroll
    for (int r = 0; r < 10; ++r) {
        const int row = r0 + rb - 1 + r;
        float4 s = make_float4(0.f, 0.f, 0.f, 0.f);
        if (row >= 0 && row < IMG_) {
#pragma unroll
            for (int gg = 0; gg < NG_; ++gg) {
                float4 u = pb[(size_t)gg * NPOS_ + row * W4_ + w4];
                s.x += u.x; s.y += u.y; s.z += u.z; s.w += u.w;
            }
        }
        C[r] = s;
    }

    // Halo scalars from neighbors (32-lane segments = one w4 row group).
    float Lw[10], Rx[10];
#pragma unroll
    for (int r = 0; r < 10; ++r) {
        float lw = __shfl_up(C[r].w, 1, 32);
        float rx = __shfl_down(C[r].x, 1, 32);
        Lw[r] = (w4 > 0)  ? lw : 0.f;
        Rx[r] = (w4 < 31) ? rx : 0.f;
    }

    const float* kw = kern + co * 9;
    const float k0 = kw[0], k1 = kw[1], k2 = kw[2];
    const float k3 = kw[3], k4 = kw[4], k5 = kw[5];
    const float k6 = kw[6], k7 = kw[7], k8 = kw[8];
    const float bv = (float)CIN_ * bias[co];

    float4* outp = reinterpret_cast<float4*>(out) + (size_t)(b * COUT_ + co) * PIX4_;

#pragma unroll
    for (int j = 0; j < 8; ++j) {                  // rows j, j+1, j+2 of C
        float4 a;
        a.x = bv + k0 * Lw[j]     + k1 * C[j].x     + k2 * C[j].y
                 + k3 * Lw[j + 1] + k4 * C[j + 1].x + k5 * C[j + 1].y
                 + k6 * Lw[j + 2] + k7 * C[j + 2].x + k8 * C[j + 2].y;
        a.y = bv + k0 * C[j].x     + k1 * C[j].y     + k2 * C[j].z
                 + k3 * C[j + 1].x + k4 * C[j + 1].y + k5 * C[j + 1].z
                 + k6 * C[j + 2].x + k7 * C[j + 2].y + k8 * C[j + 2].z;
        a.z = bv + k0 * C[j].y     + k1 * C[j].z     + k2 * C[j].w
                 + k3 * C[j + 1].y + k4 * C[j + 1].z + k5 * C[j + 1].w
                 + k6 * C[j + 2].y + k7 * C[j + 2].z + k8 * C[j + 2].w;
        a.w = bv + k0 * C[j].z     + k1 * C[j].w     + k2 * Rx[j]
                 + k3 * C[j + 1].z + k4 * C[j + 1].w + k5 * Rx[j + 1]
                 + k6 * C[j + 2].z + k7 * C[j + 2].w + k8 * Rx[j + 2];
        outp[(size_t)(r0 + rb + j) * W4_ + w4] = a;
    }
}

extern "C" void kernel_launch(void* const* d_in, const int* in_sizes, int n_in,
                              void* d_out, int out_size, void* d_ws, size_t ws_size,
                              hipStream_t stream) {
    const float* x    = (const float*)d_in[0];   // (32,64,128,128) f32
    const float* kern = (const float*)d_in[1];   // (64,3,3) f32
    const float* bias = (const float*)d_in[2];   // (64,1,1,1) f32
    float* out  = (float*)d_out;                 // (32,64,128,128) f32
    float* part = (float*)d_ws;                  // 4 x 2 MiB partial planes

    dim3 ga(NPOS_ / 256, NG_);                   // (512, 4) = 2048 blocks
    ch_sum4<<<ga, 256, 0, stream>>>(x, part);

    conv_shfl<<<dim3(B_ * COUT_ * 2), 256, 0, stream>>>(part, kern, bias, out);
}